// Round 11
// baseline (202.520 us; speedup 1.0000x reference)
//
#include <hip/hip_runtime.h>
#include <hip/hip_bf16.h>

constexpr int Bc = 16, Dc = 64, Tc = 4096, Ec = 1024;
constexpr int NROW = Bc * Tc;          // 65536 rows of dim 64
constexpr float DECAYF = 0.99f;
constexpr float OMDF   = 0.01f;
constexpr float EPSF   = 1e-5f;

typedef short bf16x8 __attribute__((ext_vector_type(8)));
typedef float f32x4  __attribute__((ext_vector_type(4)));

// ---- d_out layout (floats, ref return order) ----
constexpr size_t O_EI  = 0;         // embed_idx [B,T,D]   4194304
constexpr size_t O_QX  = 4194304;   // qx [B,D,T]          4194304
constexpr size_t O_IDX = 8388608;   // quantized_idx [B,T]   65536
constexpr size_t O_EMB = 8454144;   // new_embedding [E,D]   65536
constexpr size_t O_ESZ = 8519680;   // new_ema_size [E]       1024
constexpr size_t O_EMW = 8520704;   // new_ema_w [D,E]       65536

// ---- scratch inside d_out's [0, 8388608) floats. Produced by decomp,
// consumed by gemm/esum, only THEN overwritten by the epilogue. ----
constexpr size_t S_XH = 0;          // ushort plane 65536x64 = 2097152 floats
constexpr size_t S_XM = 2097152;
constexpr size_t S_XL = 4194304;
constexpr size_t S_EH = 6291456;    // ushort plane 1024x64 = 32768 floats
constexpr size_t S_EM = 6324224;    // = S_EH + 32768
constexpr size_t S_EL = 6356992;    // = S_EH + 65536
constexpr size_t S_E2 = 6389760;    // 1024 floats
constexpr size_t S_X2 = 6424576;    // 65536 floats (ends 6490112)
constexpr size_t S_P  = 6557696;    // esum partials [16][64][1024] = 1048576

// ---- ws layout (floats): counts[0..1024) | esum[1024..66560) | norm[66560..67584)

__device__ inline unsigned short bf16bits(float v) {
  union { __hip_bfloat16 b; unsigned short u; } c;
  c.b = __float2bfloat16(v);           // RNE
  return c.u;
}
__device__ inline float bf16val(unsigned short u) {
  union { unsigned u32; float f; } c;
  c.u32 = ((unsigned)u) << 16;         // bf16 -> f32 is exact bit expansion
  return c.f;
}
// exact 3-term split: x = h + m + l + eps, |eps| <= 2^-27 |x|
__device__ inline void split3(float x, unsigned short& h, unsigned short& m,
                              unsigned short& l) {
  h = bf16bits(x);
  float r1 = x - bf16val(h);           // exact (Sterbenz)
  m = bf16bits(r1);
  float r2 = r1 - bf16val(m);          // exact
  l = bf16bits(r2);
}

__device__ inline void pack8(unsigned short* s, uint4* dst) {
  uint4 v;
  v.x = (unsigned)s[0] | ((unsigned)s[1] << 16);
  v.y = (unsigned)s[2] | ((unsigned)s[3] << 16);
  v.z = (unsigned)s[4] | ((unsigned)s[5] << 16);
  v.w = (unsigned)s[6] | ((unsigned)s[7] << 16);
  *dst = v;
}

__device__ inline void gl_lds16(const unsigned short* g, unsigned short* l) {
  __builtin_amdgcn_global_load_lds(
      (const __attribute__((address_space(1))) void*)g,
      (__attribute__((address_space(3))) void*)l, 16, 0, 0);
}

// ---- decomp_x: lane=row; coalesced x read; x2 (exact np-pairwise); 3 planes ----
__global__ __launch_bounds__(256) void decomp_x(const float* __restrict__ x,
                                                float* __restrict__ out) {
  const int row = blockIdx.x * 256 + threadIdx.x;
  const int b = row >> 12, t = row & (Tc - 1);
  const float* xrow = x + (size_t)b * Dc * Tc + t;
  float xv[64];
  #pragma unroll
  for (int d = 0; d < Dc; ++d) xv[d] = xrow[(size_t)d * Tc];

  float x2;
  {
    #pragma clang fp contract(off)
    float r[8];
    #pragma unroll
    for (int j = 0; j < 8; ++j) r[j] = xv[j] * xv[j];
    #pragma unroll
    for (int k = 1; k < 8; ++k) {
      #pragma unroll
      for (int j = 0; j < 8; ++j) r[j] += xv[8 * k + j] * xv[8 * k + j];
    }
    x2 = ((r[0] + r[1]) + (r[2] + r[3])) + ((r[4] + r[5]) + (r[6] + r[7]));
  }
  out[S_X2 + row] = x2;

  uint4* ph = (uint4*)((unsigned short*)(out + S_XH) + (size_t)row * 64);
  uint4* pm = (uint4*)((unsigned short*)(out + S_XM) + (size_t)row * 64);
  uint4* pl = (uint4*)((unsigned short*)(out + S_XL) + (size_t)row * 64);
  #pragma unroll
  for (int k = 0; k < 8; ++k) {
    unsigned short hs[8], ms[8], ls[8];
    #pragma unroll
    for (int j = 0; j < 8; ++j) split3(xv[8 * k + j], hs[j], ms[j], ls[j]);
    pack8(hs, ph + k); pack8(ms, pm + k); pack8(ls, pl + k);
  }
}

// ---- decomp_e: thread=codeword; e2 (exact np-pairwise); 3 planes ----
__global__ __launch_bounds__(256) void decomp_e(const float* __restrict__ emb,
                                                float* __restrict__ out) {
  const int c = blockIdx.x * 256 + threadIdx.x;
  if (c >= Ec) return;
  const float* ep = emb + (size_t)c * Dc;
  float ev[64];
  #pragma unroll
  for (int d = 0; d < Dc; ++d) ev[d] = ep[d];

  float e2;
  {
    #pragma clang fp contract(off)
    float r[8];
    #pragma unroll
    for (int j = 0; j < 8; ++j) r[j] = ev[j] * ev[j];
    #pragma unroll
    for (int k = 1; k < 8; ++k) {
      #pragma unroll
      for (int j = 0; j < 8; ++j) r[j] += ev[8 * k + j] * ev[8 * k + j];
    }
    e2 = ((r[0] + r[1]) + (r[2] + r[3])) + ((r[4] + r[5]) + (r[6] + r[7]));
  }
  out[S_E2 + c] = e2;

  uint4* ph = (uint4*)((unsigned short*)(out + S_EH) + (size_t)c * 64);
  uint4* pm = (uint4*)((unsigned short*)(out + S_EM) + (size_t)c * 64);
  uint4* pl = (uint4*)((unsigned short*)(out + S_EL) + (size_t)c * 64);
  #pragma unroll
  for (int k = 0; k < 8; ++k) {
    unsigned short hs[8], ms[8], ls[8];
    #pragma unroll
    for (int j = 0; j < 8; ++j) split3(ev[8 * k + j], hs[j], ms[j], ls[j]);
    pack8(hs, ph + k); pack8(ms, pm + k); pack8(ls, pl + k);
  }
}

// ---- gemm_argmin: R10 showed 2 waves/SIMD -> pipes serialize (38% MFMA +
// 30% VALU, 51.5 us vs 21.6 us floor). Now: block = 8 waves = 4 rowgroups x
// 2 codebook-halves; 128 rows/block; grid 512 = 2 blocks/CU = 4 waves/SIMD.
// Tile = 32 cw (12 KB), 4 buffers (2 per half, dbuf) = 48 KB. Cross-half
// argmin merged via LDS with (q,idx) tie-break (half-0 idx always lower ->
// numpy first-index semantics preserved). ----
constexpr int TW = 32;                          // cw per tile; 32 tiles
constexpr int SLOTS = (TW / 16) * 3 * 2 * 64;   // 768 16B slots per tile

__global__ __launch_bounds__(512)
__attribute__((amdgpu_waves_per_eu(4, 4)))
void gemm_argmin(float* __restrict__ out) {
  __shared__ alignas(16) unsigned short lbuf[4][SLOTS * 8];  // 4 x 12 KB
  __shared__ float mq[4][4][8];                              // [rowgrp][quad][i]
  __shared__ int   mi[4][4][8];

  const int tid    = threadIdx.x;       // 0..511
  const int lane   = tid & 63;
  const int wave   = tid >> 6;          // 0..7
  const int rowgrp = wave & 3;
  const int hN     = wave >> 2;         // codebook half: cw in [hN*512, hN*512+512)
  const int col    = lane & 15;         // MFMA n / C-col
  const int quad   = lane >> 4;
  const int rowbase = blockIdx.x * 128 + rowgrp * 32;

  const unsigned short* XH = (const unsigned short*)(out + S_XH);
  const unsigned short* XM = (const unsigned short*)(out + S_XM);
  const unsigned short* XL = (const unsigned short*)(out + S_XL);
  const unsigned short* EHu = (const unsigned short*)(out + S_EH);
  const float* E2 = out + S_E2;
  const float* X2 = out + S_X2;

  // stage global tile t (cw base t*32) into lbuf[s].
  // slot = ((nt*3+pl)*2+hf)*64 + lane; 768 slots via 512 threads (waves 0-3
  // take a second full-wave pass -> LDS dest stays uniform-base + lane*16).
  auto stage = [&](int t, int s) {
    #pragma unroll
    for (int i = 0; i < 2; ++i) {
      int slot = tid + i * 512;
      if (slot < SLOTS) {
        int sl  = slot & 63;
        int sub = slot >> 6;            // 0..11
        int hf  = sub & 1;
        int pl  = (sub >> 1) % 3;
        int nt  = sub / 6;              // 0..1
        int cw  = t * TW + nt * 16 + (sl & 15);
        int q   = sl >> 4;
        const unsigned short* src =
            EHu + (size_t)pl * 65536 + (size_t)cw * 64 + hf * 32 + q * 8;
        gl_lds16(src, &lbuf[s][(size_t)slot * 8]);
      }
    }
  };

  bf16x8 a[12];                         // A-frags: a[mt*6 + plane*2 + half]
  #pragma unroll
  for (int mt = 0; mt < 2; ++mt) {
    size_t ao = (size_t)(rowbase + mt * 16 + col) * 64 + quad * 8;
    a[mt * 6 + 0] = *(const bf16x8*)(XH + ao);
    a[mt * 6 + 1] = *(const bf16x8*)(XH + ao + 32);
    a[mt * 6 + 2] = *(const bf16x8*)(XM + ao);
    a[mt * 6 + 3] = *(const bf16x8*)(XM + ao + 32);
    a[mt * 6 + 4] = *(const bf16x8*)(XL + ao);
    a[mt * 6 + 5] = *(const bf16x8*)(XL + ao + 32);
  }
  float x2v[8];
  #pragma unroll
  for (int mt = 0; mt < 2; ++mt)
    #pragma unroll
    for (int r = 0; r < 4; ++r)
      x2v[mt * 4 + r] = X2[rowbase + mt * 16 + quad * 4 + r];

  float best[8];
  int bidx[8];
  #pragma unroll
  for (int i = 0; i < 8; ++i) { best[i] = 3.4e38f; bidx[i] = 0; }

  stage(0, 0);          // half-0 tile 0
  stage(16, 2);         // half-1 tile 0

  for (int j = 0; j < 16; ++j) {
    __syncthreads();                     // stage(j) complete (vmcnt drained)
    if (j + 1 < 16) {
      stage(j + 1, (j + 1) & 1);
      stage(16 + j + 1, 2 + ((j + 1) & 1));
    }
    const unsigned short* lb = lbuf[hN * 2 + (j & 1)];

    #pragma unroll
    for (int nt = 0; nt < 2; ++nt) {
      bf16x8 bb[6];
      #pragma unroll
      for (int pl = 0; pl < 3; ++pl)
        #pragma unroll
        for (int hf = 0; hf < 2; ++hf)
          bb[pl * 2 + hf] = *(const bf16x8*)(
              lb + ((size_t)(((nt * 3 + pl) * 2 + hf) * 64 + lane)) * 8);
      const int cwv = hN * 512 + j * TW + nt * 16 + col;
      const float e2v = E2[cwv];

      f32x4 acc0 = {0.f, 0.f, 0.f, 0.f};
      f32x4 acc1 = {0.f, 0.f, 0.f, 0.f};
      const int PA[6] = {0, 0, 1, 1, 0, 2};   // products hh,hm,mh,mm,hl,lh
      const int PB[6] = {0, 1, 0, 1, 2, 0};
      #pragma unroll
      for (int p = 0; p < 6; ++p) {
        #pragma unroll
        for (int s = 0; s < 2; ++s) {
          bf16x8 bf = bb[PB[p] * 2 + s];
          acc0 = __builtin_amdgcn_mfma_f32_16x16x32_bf16(a[PA[p] * 2 + s], bf, acc0, 0, 0, 0);
          acc1 = __builtin_amdgcn_mfma_f32_16x16x32_bf16(a[6 + PA[p] * 2 + s], bf, acc1, 0, 0, 0);
        }
      }

      #pragma unroll
      for (int r = 0; r < 4; ++r) {
        {
          float q = __builtin_fmaf(-2.0f, acc0[r], e2v);  // fl(e2 - 2*dot)
          q = q + x2v[r];                                  // fl(+ x2)
          if (q < best[r]) { best[r] = q; bidx[r] = cwv; }
        }
        {
          float q = __builtin_fmaf(-2.0f, acc1[r], e2v);
          q = q + x2v[4 + r];
          if (q < best[4 + r]) { best[4 + r] = q; bidx[4 + r] = cwv; }
        }
      }
    }
  }

  // per-wave cross-lane argmin within each 16-lane col group
  float fq[8];
  int fi[8];
  #pragma unroll
  for (int i = 0; i < 8; ++i) {
    float bq = best[i];
    int bi = bidx[i];
    #pragma unroll
    for (int m = 1; m <= 8; m <<= 1) {
      float qo = __shfl_xor(bq, m, 64);
      int io = __shfl_xor(bi, m, 64);
      bool take = (qo < bq) || (qo == bq && io < bi);
      bq = take ? qo : bq;
      bi = take ? io : bi;
    }
    fq[i] = bq; fi[i] = bi;
  }

  // cross-half merge: half-1 publishes, half-0 merges (ties -> lower index,
  // and half-0 indices are always lower)
  if (hN == 1 && col == 0) {
    #pragma unroll
    for (int i = 0; i < 8; ++i) { mq[rowgrp][quad][i] = fq[i]; mi[rowgrp][quad][i] = fi[i]; }
  }
  __syncthreads();
  if (hN == 0 && col == 0) {
    #pragma unroll
    for (int i = 0; i < 8; ++i) {
      float q2 = mq[rowgrp][quad][i];
      int i2 = mi[rowgrp][quad][i];
      bool take = (q2 < fq[i]) || (q2 == fq[i] && i2 < fi[i]);
      int bi = take ? i2 : fi[i];
      int mt = i >> 2, r = i & 3;
      out[O_IDX + rowbase + mt * 16 + quad * 4 + r] = (float)bi;  // row = quad*4+reg [m89]
    }
  }
}

// ---- esum_partial: segmented reduction of x into embed_sum via LDS.
// 16 chunks x 16 slices (4 d each) = 256 blocks x 512 threads; acc stride
// 1025 so a thread's 4 atomics hit consecutive banks. ----
__global__ __launch_bounds__(512) void esum_partial(float* __restrict__ out,
                                                    float* __restrict__ ws) {
  const int c = blockIdx.x;       // row chunk, 4096 rows
  const int s = blockIdx.y;       // d-slice of 4
  __shared__ float acc[4 * 1025];
  __shared__ float cnt[1024];
  for (int i = threadIdx.x; i < 4 * 1025; i += 512) acc[i] = 0.f;
  if (s == 0)
    for (int i = threadIdx.x; i < 1024; i += 512) cnt[i] = 0.f;
  __syncthreads();

  const unsigned short* XH = (const unsigned short*)(out + S_XH);
  const unsigned short* XM = (const unsigned short*)(out + S_XM);
  const unsigned short* XL = (const unsigned short*)(out + S_XL);

  #pragma unroll 2
  for (int it = 0; it < 8; ++it) {
    const int r = c * 4096 + it * 512 + threadIdx.x;
    const int bi = (int)out[O_IDX + r];
    const size_t off = (size_t)r * 64 + s * 4;
    const uint2 h = *(const uint2*)(XH + off);
    const uint2 m = *(const uint2*)(XM + off);
    const uint2 l = *(const uint2*)(XL + off);

#define DOPAIR(k, HW, MW, LW)                                                  \
    {                                                                          \
      float v0 = (bf16val((unsigned short)(HW)) +                              \
                  bf16val((unsigned short)(MW))) +                             \
                 bf16val((unsigned short)(LW));                                \
      float v1 = (bf16val((unsigned short)((HW) >> 16)) +                      \
                  bf16val((unsigned short)((MW) >> 16))) +                     \
                 bf16val((unsigned short)((LW) >> 16));                        \
      atomicAdd(&acc[(2 * (k) + 0) * 1025 + bi], v0);                          \
      atomicAdd(&acc[(2 * (k) + 1) * 1025 + bi], v1);                          \
    }
    DOPAIR(0, h.x, m.x, l.x)
    DOPAIR(1, h.y, m.y, l.y)
#undef DOPAIR
    if (s == 0) atomicAdd(&cnt[bi], 1.0f);
  }
  __syncthreads();

  float* part = out + S_P + ((size_t)c * 64 + s * 4) * 1024;
  for (int i = threadIdx.x; i < 4096; i += 512)
    part[i] = acc[(i >> 10) * 1025 + (i & 1023)];
  if (s == 0)
    for (int i = threadIdx.x; i < 1024; i += 512)
      atomicAdd(&ws[i], cnt[i]);
}

// ---- esum_reduce: esum[i] = sum over 16 chunk partials ----
__global__ __launch_bounds__(256) void esum_reduce(const float* __restrict__ out,
                                                   float* __restrict__ ws) {
  const int i = blockIdx.x * 256 + threadIdx.x;  // 0..65535 (= d*1024+e)
  float v = 0.f;
  #pragma unroll
  for (int c = 0; c < 16; ++c) v += out[S_P + (size_t)c * 65536 + i];
  ws[1024 + i] = v;
}

// ---- epilogue: pure streaming: read x/idx, gather emb, write embed_idx+qx ----
__global__ __launch_bounds__(256) void epilogue_kernel(
    const float* __restrict__ x, const float* __restrict__ emb,
    float* __restrict__ out) {
  const int row = blockIdx.x * 256 + threadIdx.x;
  const int b = row >> 12, t = row & (Tc - 1);
  const float* xrow = x + (size_t)b * Dc * Tc + t;

  const int bi = (int)out[O_IDX + row];

  const float4* eb = (const float4*)(emb + (size_t)bi * Dc);
  float* qx_base = out + O_QX + (size_t)b * Dc * Tc + t;
  float4* ei_base = (float4*)(out + O_EI + (size_t)row * Dc);

  #pragma unroll
  for (int k = 0; k < 16; ++k) {
    float4 ev = eb[k];
    ei_base[k] = ev;
    {
      const int d = 4 * k + 0; float xd = xrow[(size_t)d * Tc];
      float diff = ev.x - xd;
      qx_base[(size_t)d * Tc] = xd + diff;
    }
    {
      const int d = 4 * k + 1; float xd = xrow[(size_t)d * Tc];
      float diff = ev.y - xd;
      qx_base[(size_t)d * Tc] = xd + diff;
    }
    {
      const int d = 4 * k + 2; float xd = xrow[(size_t)d * Tc];
      float diff = ev.z - xd;
      qx_base[(size_t)d * Tc] = xd + diff;
    }
    {
      const int d = 4 * k + 3; float xd = xrow[(size_t)d * Tc];
      float diff = ev.w - xd;
      qx_base[(size_t)d * Tc] = xd + diff;
    }
  }
}

// ---- finalize_a: ema_size update + normalization ----
__global__ __launch_bounds__(1024) void finalize_a(
    const float* __restrict__ ema_size, float* __restrict__ ws,
    float* __restrict__ out) {
  const int e = threadIdx.x;
  float ns = DECAYF * ema_size[e] + OMDF * ws[e];
  __shared__ float red[1024];
  red[e] = ns;
  __syncthreads();
  for (int s = 512; s > 0; s >>= 1) {
    if (e < s) red[e] += red[e + s];
    __syncthreads();
  }
  float n = red[0];
  float v = ((ns + EPSF) / (n + (float)Ec * EPSF)) * n;
  out[O_ESZ + e] = v;
  ws[66560 + e] = v;
}

// ---- finalize_b: new_ema_w + new_embedding ----
__global__ __launch_bounds__(256) void finalize_b(
    const float* __restrict__ ema_w, const float* __restrict__ ws,
    float* __restrict__ out) {
  int i = blockIdx.x * 256 + threadIdx.x;  // i = d*E + e
  int d = i >> 10;
  int e = i & (Ec - 1);
  float w = DECAYF * ema_w[i] + OMDF * ws[1024 + i];
  out[O_EMW + i] = w;
  out[O_EMB + e * Dc + d] = w / ws[66560 + e];
}

extern "C" void kernel_launch(void* const* d_in, const int* in_sizes, int n_in,
                              void* d_out, int out_size, void* d_ws, size_t ws_size,
                              hipStream_t stream) {
  const float* x        = (const float*)d_in[0];
  const float* emb      = (const float*)d_in[1];
  const float* ema_size = (const float*)d_in[2];
  const float* ema_w    = (const float*)d_in[3];
  float* out = (float*)d_out;
  float* ws  = (float*)d_ws;

  (void)hipMemsetAsync(ws, 0, 1024 * sizeof(float), stream);  // counts only
  decomp_x<<<NROW / 256, 256, 0, stream>>>(x, out);
  decomp_e<<<Ec / 256, 256, 0, stream>>>(emb, out);
  gemm_argmin<<<NROW / 128, 512, 0, stream>>>(out);
  esum_partial<<<dim3(16, 16), 512, 0, stream>>>(out, ws);
  esum_reduce<<<NROW / 256, 256, 0, stream>>>(out, ws);
  epilogue_kernel<<<NROW / 256, 256, 0, stream>>>(x, emb, out);
  finalize_a<<<1, 1024, 0, stream>>>(ema_size, ws, out);
  finalize_b<<<Ec * Dc / 256, 256, 0, stream>>>(ema_w, ws, out);
}

// Round 12
// 190.060 us; speedup vs baseline: 1.0656x; 1.0656x over previous
//
#include <hip/hip_runtime.h>
#include <hip/hip_bf16.h>

constexpr int Bc = 16, Dc = 64, Tc = 4096, Ec = 1024;
constexpr int NROW = Bc * Tc;          // 65536 rows of dim 64
constexpr float DECAYF = 0.99f;
constexpr float OMDF   = 0.01f;
constexpr float EPSF   = 1e-5f;

typedef short bf16x8 __attribute__((ext_vector_type(8)));
typedef float f32x4  __attribute__((ext_vector_type(4)));

// ---- d_out layout (floats, ref return order) ----
constexpr size_t O_EI  = 0;         // embed_idx [B,T,D]   4194304
constexpr size_t O_QX  = 4194304;   // qx [B,D,T]          4194304
constexpr size_t O_IDX = 8388608;   // quantized_idx [B,T]   65536
constexpr size_t O_EMB = 8454144;   // new_embedding [E,D]   65536
constexpr size_t O_ESZ = 8519680;   // new_ema_size [E]       1024
constexpr size_t O_EMW = 8520704;   // new_ema_w [D,E]       65536

// ---- scratch inside d_out's [0, 8388608) floats. Produced by decomp,
// consumed by gemm/esum, only THEN overwritten by the epilogue. ----
constexpr size_t S_XH = 0;          // ushort plane 65536x64 = 2097152 floats
constexpr size_t S_XM = 2097152;
constexpr size_t S_XL = 4194304;
constexpr size_t S_EH = 6291456;    // ushort plane 1024x64 = 32768 floats
constexpr size_t S_EM = 6324224;    // = S_EH + 32768
constexpr size_t S_EL = 6356992;    // = S_EH + 65536
constexpr size_t S_E2 = 6389760;    // 1024 floats
constexpr size_t S_X2 = 6424576;    // 65536 floats (ends 6490112)
constexpr size_t S_P  = 6557696;    // esum partials [16][64][1024] = 1048576

// ---- ws layout (floats): counts[0..1024) | (unused) | norm[66560..67584)

__device__ inline unsigned short bf16bits(float v) {
  union { __hip_bfloat16 b; unsigned short u; } c;
  c.b = __float2bfloat16(v);           // RNE
  return c.u;
}
__device__ inline float bf16val(unsigned short u) {
  union { unsigned u32; float f; } c;
  c.u32 = ((unsigned)u) << 16;         // bf16 -> f32 is exact bit expansion
  return c.f;
}
// exact 3-term split: x = h + m + l + eps, |eps| <= 2^-27 |x|
__device__ inline void split3(float x, unsigned short& h, unsigned short& m,
                              unsigned short& l) {
  h = bf16bits(x);
  float r1 = x - bf16val(h);           // exact (Sterbenz)
  m = bf16bits(r1);
  float r2 = r1 - bf16val(m);          // exact
  l = bf16bits(r2);
}

__device__ inline void pack8(unsigned short* s, uint4* dst) {
  uint4 v;
  v.x = (unsigned)s[0] | ((unsigned)s[1] << 16);
  v.y = (unsigned)s[2] | ((unsigned)s[3] << 16);
  v.z = (unsigned)s[4] | ((unsigned)s[5] << 16);
  v.w = (unsigned)s[6] | ((unsigned)s[7] << 16);
  *dst = v;
}

__device__ inline void gl_lds16(const unsigned short* g, unsigned short* l) {
  __builtin_amdgcn_global_load_lds(
      (const __attribute__((address_space(1))) void*)g,
      (__attribute__((address_space(3))) void*)l, 16, 0, 0);
}

// ---- decomp_x: lane=row; coalesced x read; x2 (exact np-pairwise); 3 planes ----
__global__ __launch_bounds__(256) void decomp_x(const float* __restrict__ x,
                                                float* __restrict__ out) {
  const int row = blockIdx.x * 256 + threadIdx.x;
  const int b = row >> 12, t = row & (Tc - 1);
  const float* xrow = x + (size_t)b * Dc * Tc + t;
  float xv[64];
  #pragma unroll
  for (int d = 0; d < Dc; ++d) xv[d] = xrow[(size_t)d * Tc];

  float x2;
  {
    #pragma clang fp contract(off)
    float r[8];
    #pragma unroll
    for (int j = 0; j < 8; ++j) r[j] = xv[j] * xv[j];
    #pragma unroll
    for (int k = 1; k < 8; ++k) {
      #pragma unroll
      for (int j = 0; j < 8; ++j) r[j] += xv[8 * k + j] * xv[8 * k + j];
    }
    x2 = ((r[0] + r[1]) + (r[2] + r[3])) + ((r[4] + r[5]) + (r[6] + r[7]));
  }
  out[S_X2 + row] = x2;

  uint4* ph = (uint4*)((unsigned short*)(out + S_XH) + (size_t)row * 64);
  uint4* pm = (uint4*)((unsigned short*)(out + S_XM) + (size_t)row * 64);
  uint4* pl = (uint4*)((unsigned short*)(out + S_XL) + (size_t)row * 64);
  #pragma unroll
  for (int k = 0; k < 8; ++k) {
    unsigned short hs[8], ms[8], ls[8];
    #pragma unroll
    for (int j = 0; j < 8; ++j) split3(xv[8 * k + j], hs[j], ms[j], ls[j]);
    pack8(hs, ph + k); pack8(ms, pm + k); pack8(ls, pl + k);
  }
}

// ---- decomp_e: thread=codeword; e2; 3 planes; also zeroes counts (replaces
// the hipMemsetAsync dispatch — stream order guarantees it lands before
// esum_partial's atomics). ----
__global__ __launch_bounds__(256) void decomp_e(const float* __restrict__ emb,
                                                float* __restrict__ out,
                                                float* __restrict__ ws) {
  const int c = blockIdx.x * 256 + threadIdx.x;
  if (c < 1024) ws[c] = 0.0f;          // counts
  if (c >= Ec) return;
  const float* ep = emb + (size_t)c * Dc;
  float ev[64];
  #pragma unroll
  for (int d = 0; d < Dc; ++d) ev[d] = ep[d];

  float e2;
  {
    #pragma clang fp contract(off)
    float r[8];
    #pragma unroll
    for (int j = 0; j < 8; ++j) r[j] = ev[j] * ev[j];
    #pragma unroll
    for (int k = 1; k < 8; ++k) {
      #pragma unroll
      for (int j = 0; j < 8; ++j) r[j] += ev[8 * k + j] * ev[8 * k + j];
    }
    e2 = ((r[0] + r[1]) + (r[2] + r[3])) + ((r[4] + r[5]) + (r[6] + r[7]));
  }
  out[S_E2 + c] = e2;

  uint4* ph = (uint4*)((unsigned short*)(out + S_EH) + (size_t)c * 64);
  uint4* pm = (uint4*)((unsigned short*)(out + S_EM) + (size_t)c * 64);
  uint4* pl = (uint4*)((unsigned short*)(out + S_EL) + (size_t)c * 64);
  #pragma unroll
  for (int k = 0; k < 8; ++k) {
    unsigned short hs[8], ms[8], ls[8];
    #pragma unroll
    for (int j = 0; j < 8; ++j) split3(ev[8 * k + j], hs[j], ms[j], ls[j]);
    pack8(hs, ph + k); pack8(ms, pm + k); pack8(ls, pl + k);
  }
}

// ---- gemm_argmin: R10 structure (proven 51.5 us): 8 waves x 32 rows, all
// waves scan all 1024 cw, B LDS-staged fragment-major, 2 waves/SIMD.
// R11 lesson: more waves/SIMD LOSES (remat gets worse: VGPR 64, 60 us).
// NEW: asm register pins on the A-frags/x2v defeat the allocator's
// rematerialize-from-global heuristic (the R7/R8/R11 recurring villain) —
// budget at 2 waves/EU is 256 VGPR, so residency is free. ----
constexpr int TW = 64;              // cw per tile; 16 tiles
constexpr int SLOTS = (TW / 16) * 3 * 2 * 64;  // 16B slots per tile = 1536

__global__ __launch_bounds__(512)
__attribute__((amdgpu_waves_per_eu(2, 2)))
void gemm_argmin(float* __restrict__ out) {
  __shared__ alignas(16) unsigned short lbuf[2][SLOTS * 8];  // 2 x 24 KB

  const int tid  = threadIdx.x;       // 0..511
  const int lane = tid & 63;
  const int wave = tid >> 6;          // 0..7
  const int col  = lane & 15;         // MFMA n / C-col
  const int quad = lane >> 4;
  const int rowbase = blockIdx.x * 256 + wave * 32;

  const unsigned short* XH = (const unsigned short*)(out + S_XH);
  const unsigned short* XM = (const unsigned short*)(out + S_XM);
  const unsigned short* XL = (const unsigned short*)(out + S_XL);
  const unsigned short* EHu = (const unsigned short*)(out + S_EH);
  const float* E2 = out + S_E2;
  const float* X2 = out + S_X2;

  // stage tile tl into lbuf[s]: slot = ((nt*3+pl)*2+half)*64 + lane
  auto stage = [&](int tl, int s) {
    #pragma unroll
    for (int i = 0; i < 3; ++i) {
      int slot = tid + i * 512;       // 0..1535
      int sl   = slot & 63;
      int sub  = slot >> 6;           // 0..23
      int half = sub & 1;
      int pl   = (sub >> 1) % 3;
      int nt   = sub / 6;             // 0..3
      int cw   = tl * TW + nt * 16 + (sl & 15);
      int q    = sl >> 4;
      const unsigned short* src =
          EHu + (size_t)pl * 65536 + (size_t)cw * 64 + half * 32 + q * 8;
      gl_lds16(src, &lbuf[s][(size_t)slot * 8]);
    }
  };

  bf16x8 a[12];                       // A-frags: a[mt*6 + plane*2 + half]
  #pragma unroll
  for (int mt = 0; mt < 2; ++mt) {
    size_t ao = (size_t)(rowbase + mt * 16 + col) * 64 + quad * 8;
    a[mt * 6 + 0] = *(const bf16x8*)(XH + ao);
    a[mt * 6 + 1] = *(const bf16x8*)(XH + ao + 32);
    a[mt * 6 + 2] = *(const bf16x8*)(XM + ao);
    a[mt * 6 + 3] = *(const bf16x8*)(XM + ao + 32);
    a[mt * 6 + 4] = *(const bf16x8*)(XL + ao);
    a[mt * 6 + 5] = *(const bf16x8*)(XL + ao + 32);
  }
  float x2v[8];
  #pragma unroll
  for (int mt = 0; mt < 2; ++mt)
    #pragma unroll
    for (int r = 0; r < 4; ++r)
      x2v[mt * 4 + r] = X2[rowbase + mt * 16 + quad * 4 + r];

  // PIN: make these values opaque so the allocator cannot rematerialize
  // them from their global loads inside the K-loop.
  #pragma unroll
  for (int i = 0; i < 12; ++i) asm volatile("" : "+v"(a[i]));
  #pragma unroll
  for (int i = 0; i < 8; ++i) asm volatile("" : "+v"(x2v[i]));

  float best[8];
  int bidx[8];
  #pragma unroll
  for (int i = 0; i < 8; ++i) { best[i] = 3.4e38f; bidx[i] = 0; }

  stage(0, 0);

  for (int tl = 0; tl < Ec / TW; ++tl) {
    __syncthreads();                   // stage(tl) complete (vmcnt drained)
    if (tl + 1 < Ec / TW) stage(tl + 1, (tl + 1) & 1);
    const unsigned short* lb = lbuf[tl & 1];

    #pragma unroll
    for (int nt4 = 0; nt4 < TW / 16; ++nt4) {
      bf16x8 bb[6];
      #pragma unroll
      for (int pl = 0; pl < 3; ++pl)
        #pragma unroll
        for (int h = 0; h < 2; ++h)
          bb[pl * 2 + h] = *(const bf16x8*)(
              lb + ((size_t)(((nt4 * 3 + pl) * 2 + h) * 64 + lane)) * 8);
      const float e2v = E2[tl * TW + nt4 * 16 + col];

      f32x4 acc0 = {0.f, 0.f, 0.f, 0.f};
      f32x4 acc1 = {0.f, 0.f, 0.f, 0.f};
      const int PA[6] = {0, 0, 1, 1, 0, 2};   // products hh,hm,mh,mm,hl,lh
      const int PB[6] = {0, 1, 0, 1, 2, 0};
      #pragma unroll
      for (int p = 0; p < 6; ++p) {
        #pragma unroll
        for (int s = 0; s < 2; ++s) {
          bf16x8 bf = bb[PB[p] * 2 + s];
          acc0 = __builtin_amdgcn_mfma_f32_16x16x32_bf16(a[PA[p] * 2 + s], bf, acc0, 0, 0, 0);
          acc1 = __builtin_amdgcn_mfma_f32_16x16x32_bf16(a[6 + PA[p] * 2 + s], bf, acc1, 0, 0, 0);
        }
      }

      const int cwv = tl * TW + nt4 * 16 + col;
      #pragma unroll
      for (int r = 0; r < 4; ++r) {
        {
          float q = __builtin_fmaf(-2.0f, acc0[r], e2v);  // fl(e2 - 2*dot)
          q = q + x2v[r];                                  // fl(+ x2)
          if (q < best[r]) { best[r] = q; bidx[r] = cwv; }
        }
        {
          float q = __builtin_fmaf(-2.0f, acc1[r], e2v);
          q = q + x2v[4 + r];
          if (q < best[4 + r]) { best[4 + r] = q; bidx[4 + r] = cwv; }
        }
      }
    }
  }

  // cross-lane argmin within each 16-lane col group (ties -> lowest cw index)
  #pragma unroll
  for (int i = 0; i < 8; ++i) {
    float bq = best[i];
    int bi = bidx[i];
    #pragma unroll
    for (int m = 1; m <= 8; m <<= 1) {
      float qo = __shfl_xor(bq, m, 64);
      int io = __shfl_xor(bi, m, 64);
      bool take = (qo < bq) || (qo == bq && io < bi);
      bq = take ? qo : bq;
      bi = take ? io : bi;
    }
    if (col == 0) {
      int mt = i >> 2, r = i & 3;
      int row = rowbase + mt * 16 + quad * 4 + r;
      out[O_IDX + row] = (float)bi;   // C row = quad*4+reg [m89]
    }
  }
}

// ---- esum_partial: segmented reduction of x into embed_sum via LDS.
// 16 chunks x 16 slices (4 d each) = 256 blocks x 512 threads; acc stride
// 1025 so a thread's 4 atomics hit consecutive banks. ----
__global__ __launch_bounds__(512) void esum_partial(float* __restrict__ out,
                                                    float* __restrict__ ws) {
  const int c = blockIdx.x;       // row chunk, 4096 rows
  const int s = blockIdx.y;       // d-slice of 4
  __shared__ float acc[4 * 1025];
  __shared__ float cnt[1024];
  for (int i = threadIdx.x; i < 4 * 1025; i += 512) acc[i] = 0.f;
  if (s == 0)
    for (int i = threadIdx.x; i < 1024; i += 512) cnt[i] = 0.f;
  __syncthreads();

  const unsigned short* XH = (const unsigned short*)(out + S_XH);
  const unsigned short* XM = (const unsigned short*)(out + S_XM);
  const unsigned short* XL = (const unsigned short*)(out + S_XL);

  #pragma unroll 2
  for (int it = 0; it < 8; ++it) {
    const int r = c * 4096 + it * 512 + threadIdx.x;
    const int bi = (int)out[O_IDX + r];
    const size_t off = (size_t)r * 64 + s * 4;
    const uint2 h = *(const uint2*)(XH + off);
    const uint2 m = *(const uint2*)(XM + off);
    const uint2 l = *(const uint2*)(XL + off);

#define DOPAIR(k, HW, MW, LW)                                                  \
    {                                                                          \
      float v0 = (bf16val((unsigned short)(HW)) +                              \
                  bf16val((unsigned short)(MW))) +                             \
                 bf16val((unsigned short)(LW));                                \
      float v1 = (bf16val((unsigned short)((HW) >> 16)) +                      \
                  bf16val((unsigned short)((MW) >> 16))) +                     \
                 bf16val((unsigned short)((LW) >> 16));                        \
      atomicAdd(&acc[(2 * (k) + 0) * 1025 + bi], v0);                          \
      atomicAdd(&acc[(2 * (k) + 1) * 1025 + bi], v1);                          \
    }
    DOPAIR(0, h.x, m.x, l.x)
    DOPAIR(1, h.y, m.y, l.y)
#undef DOPAIR
    if (s == 0) atomicAdd(&cnt[bi], 1.0f);
  }
  __syncthreads();

  float* part = out + S_P + ((size_t)c * 64 + s * 4) * 1024;
  for (int i = threadIdx.x; i < 4096; i += 512)
    part[i] = acc[(i >> 10) * 1025 + (i & 1023)];
  if (s == 0)
    for (int i = threadIdx.x; i < 1024; i += 512)
      atomicAdd(&ws[i], cnt[i]);
}

// ---- finalize_a: ema_size update + normalization (needs only counts) ----
__global__ __launch_bounds__(1024) void finalize_a(
    const float* __restrict__ ema_size, float* __restrict__ ws,
    float* __restrict__ out) {
  const int e = threadIdx.x;
  float ns = DECAYF * ema_size[e] + OMDF * ws[e];
  __shared__ float red[1024];
  red[e] = ns;
  __syncthreads();
  for (int s = 512; s > 0; s >>= 1) {
    if (e < s) red[e] += red[e + s];
    __syncthreads();
  }
  float n = red[0];
  float v = ((ns + EPSF) / (n + (float)Ec * EPSF)) * n;
  out[O_ESZ + e] = v;
  ws[66560 + e] = v;                   // norm
}

// ---- esum_finalize_w: fused esum_reduce + finalize_b — sums the 16 chunk
// partials and immediately produces new_ema_w + new_embedding (removes the
// 4 MB esum round-trip through ws and one dispatch). ----
__global__ __launch_bounds__(256) void esum_finalize_w(
    const float* __restrict__ ema_w, const float* __restrict__ ws,
    float* __restrict__ out) {
  const int i = blockIdx.x * 256 + threadIdx.x;  // 0..65535 (= d*1024+e)
  float v = 0.f;
  #pragma unroll
  for (int c = 0; c < 16; ++c) v += out[S_P + (size_t)c * 65536 + i];
  int d = i >> 10;
  int e = i & (Ec - 1);
  float w = DECAYF * ema_w[i] + OMDF * v;
  out[O_EMW + i] = w;
  out[O_EMB + e * Dc + d] = w / ws[66560 + e];
}

// ---- epilogue: pure streaming: read x/idx, gather emb, write embed_idx+qx ----
__global__ __launch_bounds__(256) void epilogue_kernel(
    const float* __restrict__ x, const float* __restrict__ emb,
    float* __restrict__ out) {
  const int row = blockIdx.x * 256 + threadIdx.x;
  const int b = row >> 12, t = row & (Tc - 1);
  const float* xrow = x + (size_t)b * Dc * Tc + t;

  const int bi = (int)out[O_IDX + row];

  const float4* eb = (const float4*)(emb + (size_t)bi * Dc);
  float* qx_base = out + O_QX + (size_t)b * Dc * Tc + t;
  float4* ei_base = (float4*)(out + O_EI + (size_t)row * Dc);

  #pragma unroll
  for (int k = 0; k < 16; ++k) {
    float4 ev = eb[k];
    ei_base[k] = ev;
    {
      const int d = 4 * k + 0; float xd = xrow[(size_t)d * Tc];
      float diff = ev.x - xd;
      qx_base[(size_t)d * Tc] = xd + diff;
    }
    {
      const int d = 4 * k + 1; float xd = xrow[(size_t)d * Tc];
      float diff = ev.y - xd;
      qx_base[(size_t)d * Tc] = xd + diff;
    }
    {
      const int d = 4 * k + 2; float xd = xrow[(size_t)d * Tc];
      float diff = ev.z - xd;
      qx_base[(size_t)d * Tc] = xd + diff;
    }
    {
      const int d = 4 * k + 3; float xd = xrow[(size_t)d * Tc];
      float diff = ev.w - xd;
      qx_base[(size_t)d * Tc] = xd + diff;
    }
  }
}

extern "C" void kernel_launch(void* const* d_in, const int* in_sizes, int n_in,
                              void* d_out, int out_size, void* d_ws, size_t ws_size,
                              hipStream_t stream) {
  const float* x        = (const float*)d_in[0];
  const float* emb      = (const float*)d_in[1];
  const float* ema_size = (const float*)d_in[2];
  const float* ema_w    = (const float*)d_in[3];
  float* out = (float*)d_out;
  float* ws  = (float*)d_ws;

  decomp_x<<<NROW / 256, 256, 0, stream>>>(x, out);
  decomp_e<<<Ec / 256, 256, 0, stream>>>(emb, out, ws);   // also zeroes counts
  gemm_argmin<<<NROW / 256, 512, 0, stream>>>(out);
  esum_partial<<<dim3(16, 16), 512, 0, stream>>>(out, ws);
  finalize_a<<<1, 1024, 0, stream>>>(ema_size, ws, out);
  esum_finalize_w<<<Ec * Dc / 256, 256, 0, stream>>>(ema_w, ws, out);
  epilogue_kernel<<<NROW / 256, 256, 0, stream>>>(x, emb, out);
}

// Round 13
// 187.970 us; speedup vs baseline: 1.0774x; 1.0111x over previous
//
#include <hip/hip_runtime.h>
#include <hip/hip_bf16.h>

constexpr int Bc = 16, Dc = 64, Tc = 4096, Ec = 1024;
constexpr int NROW = Bc * Tc;          // 65536 rows of dim 64
constexpr float DECAYF = 0.99f;
constexpr float OMDF   = 0.01f;
constexpr float EPSF   = 1e-5f;

typedef short bf16x8 __attribute__((ext_vector_type(8)));
typedef float f32x4  __attribute__((ext_vector_type(4)));

// ---- d_out layout (floats, ref return order) ----
constexpr size_t O_EI  = 0;         // embed_idx [B,T,D]   4194304
constexpr size_t O_QX  = 4194304;   // qx [B,D,T]          4194304
constexpr size_t O_IDX = 8388608;   // quantized_idx [B,T]   65536
constexpr size_t O_EMB = 8454144;   // new_embedding [E,D]   65536
constexpr size_t O_ESZ = 8519680;   // new_ema_size [E]       1024
constexpr size_t O_EMW = 8520704;   // new_ema_w [D,E]       65536

// ---- scratch inside d_out's [0, 8388608) floats. Produced by decomp,
// consumed by gemm/esum, only THEN overwritten by the epilogue. ----
constexpr size_t S_XH = 0;          // ushort plane 65536x64 = 2097152 floats
constexpr size_t S_XM = 2097152;
constexpr size_t S_XL = 4194304;
constexpr size_t S_EH = 6291456;    // ushort plane 1024x64 = 32768 floats
constexpr size_t S_EM = 6324224;    // = S_EH + 32768
constexpr size_t S_EL = 6356992;    // = S_EH + 65536
constexpr size_t S_E2 = 6389760;    // 1024 floats
constexpr size_t S_X2 = 6424576;    // 65536 floats (ends 6490112)
constexpr size_t S_P  = 6557696;    // esum partials [16][64][1024] = 1048576

// ---- ws layout (floats): counts[0..1024) | (unused) | norm[66560..67584)

__device__ inline unsigned short bf16bits(float v) {
  union { __hip_bfloat16 b; unsigned short u; } c;
  c.b = __float2bfloat16(v);           // RNE
  return c.u;
}
__device__ inline float bf16val(unsigned short u) {
  union { unsigned u32; float f; } c;
  c.u32 = ((unsigned)u) << 16;         // bf16 -> f32 is exact bit expansion
  return c.f;
}
// exact 3-term split: x = h + m + l + eps, |eps| <= 2^-27 |x|
__device__ inline void split3(float x, unsigned short& h, unsigned short& m,
                              unsigned short& l) {
  h = bf16bits(x);
  float r1 = x - bf16val(h);           // exact (Sterbenz)
  m = bf16bits(r1);
  float r2 = r1 - bf16val(m);          // exact
  l = bf16bits(r2);
}

__device__ inline void pack8(unsigned short* s, uint4* dst) {
  uint4 v;
  v.x = (unsigned)s[0] | ((unsigned)s[1] << 16);
  v.y = (unsigned)s[2] | ((unsigned)s[3] << 16);
  v.z = (unsigned)s[4] | ((unsigned)s[5] << 16);
  v.w = (unsigned)s[6] | ((unsigned)s[7] << 16);
  *dst = v;
}

__device__ inline void gl_lds16(const unsigned short* g, unsigned short* l) {
  __builtin_amdgcn_global_load_lds(
      (const __attribute__((address_space(1))) void*)g,
      (__attribute__((address_space(3))) void*)l, 16, 0, 0);
}

// ---- decomp_x: lane=row; coalesced x read; x2 (exact np-pairwise); 3 planes ----
__global__ __launch_bounds__(256) void decomp_x(const float* __restrict__ x,
                                                float* __restrict__ out) {
  const int row = blockIdx.x * 256 + threadIdx.x;
  const int b = row >> 12, t = row & (Tc - 1);
  const float* xrow = x + (size_t)b * Dc * Tc + t;
  float xv[64];
  #pragma unroll
  for (int d = 0; d < Dc; ++d) xv[d] = xrow[(size_t)d * Tc];

  float x2;
  {
    #pragma clang fp contract(off)
    float r[8];
    #pragma unroll
    for (int j = 0; j < 8; ++j) r[j] = xv[j] * xv[j];
    #pragma unroll
    for (int k = 1; k < 8; ++k) {
      #pragma unroll
      for (int j = 0; j < 8; ++j) r[j] += xv[8 * k + j] * xv[8 * k + j];
    }
    x2 = ((r[0] + r[1]) + (r[2] + r[3])) + ((r[4] + r[5]) + (r[6] + r[7]));
  }
  out[S_X2 + row] = x2;

  uint4* ph = (uint4*)((unsigned short*)(out + S_XH) + (size_t)row * 64);
  uint4* pm = (uint4*)((unsigned short*)(out + S_XM) + (size_t)row * 64);
  uint4* pl = (uint4*)((unsigned short*)(out + S_XL) + (size_t)row * 64);
  #pragma unroll
  for (int k = 0; k < 8; ++k) {
    unsigned short hs[8], ms[8], ls[8];
    #pragma unroll
    for (int j = 0; j < 8; ++j) split3(xv[8 * k + j], hs[j], ms[j], ls[j]);
    pack8(hs, ph + k); pack8(ms, pm + k); pack8(ls, pl + k);
  }
}

// ---- decomp_e: thread=codeword; e2; 3 planes; also zeroes counts ----
__global__ __launch_bounds__(256) void decomp_e(const float* __restrict__ emb,
                                                float* __restrict__ out,
                                                float* __restrict__ ws) {
  const int c = blockIdx.x * 256 + threadIdx.x;
  if (c < 1024) ws[c] = 0.0f;          // counts
  if (c >= Ec) return;
  const float* ep = emb + (size_t)c * Dc;
  float ev[64];
  #pragma unroll
  for (int d = 0; d < Dc; ++d) ev[d] = ep[d];

  float e2;
  {
    #pragma clang fp contract(off)
    float r[8];
    #pragma unroll
    for (int j = 0; j < 8; ++j) r[j] = ev[j] * ev[j];
    #pragma unroll
    for (int k = 1; k < 8; ++k) {
      #pragma unroll
      for (int j = 0; j < 8; ++j) r[j] += ev[8 * k + j] * ev[8 * k + j];
    }
    e2 = ((r[0] + r[1]) + (r[2] + r[3])) + ((r[4] + r[5]) + (r[6] + r[7]));
  }
  out[S_E2 + c] = e2;

  uint4* ph = (uint4*)((unsigned short*)(out + S_EH) + (size_t)c * 64);
  uint4* pm = (uint4*)((unsigned short*)(out + S_EM) + (size_t)c * 64);
  uint4* pl = (uint4*)((unsigned short*)(out + S_EL) + (size_t)c * 64);
  #pragma unroll
  for (int k = 0; k < 8; ++k) {
    unsigned short hs[8], ms[8], ls[8];
    #pragma unroll
    for (int j = 0; j < 8; ++j) split3(ev[8 * k + j], hs[j], ms[j], ls[j]);
    pack8(hs, ph + k); pack8(ms, pm + k); pack8(ls, pl + k);
  }
}

// ---- gemm_argmin: R10 structure + PAIRED N-tiles. R12 falsified remat here
// (VGPR=88 fits all frags); real limiter is MFMA dependent-chain latency at
// 2 chains/wave. Now each iteration processes TWO 16-cw N-tiles with 4
// independent acc chains/wave (8/SIMD). Interleaving across chains does NOT
// reorder within-chain accumulation -> bit-identical scores to R10/R12. ----
constexpr int TW = 64;              // cw per tile; 16 tiles
constexpr int SLOTS = (TW / 16) * 3 * 2 * 64;  // 16B slots per tile = 1536

__global__ __launch_bounds__(512)
__attribute__((amdgpu_waves_per_eu(2, 2)))
void gemm_argmin(float* __restrict__ out) {
  __shared__ alignas(16) unsigned short lbuf[2][SLOTS * 8];  // 2 x 24 KB

  const int tid  = threadIdx.x;       // 0..511
  const int lane = tid & 63;
  const int wave = tid >> 6;          // 0..7
  const int col  = lane & 15;         // MFMA n / C-col
  const int quad = lane >> 4;
  const int rowbase = blockIdx.x * 256 + wave * 32;

  const unsigned short* XH = (const unsigned short*)(out + S_XH);
  const unsigned short* XM = (const unsigned short*)(out + S_XM);
  const unsigned short* XL = (const unsigned short*)(out + S_XL);
  const unsigned short* EHu = (const unsigned short*)(out + S_EH);
  const float* E2 = out + S_E2;
  const float* X2 = out + S_X2;

  // stage tile tl into lbuf[s]: slot = ((nt*3+pl)*2+half)*64 + lane
  auto stage = [&](int tl, int s) {
    #pragma unroll
    for (int i = 0; i < 3; ++i) {
      int slot = tid + i * 512;       // 0..1535
      int sl   = slot & 63;
      int sub  = slot >> 6;           // 0..23
      int half = sub & 1;
      int pl   = (sub >> 1) % 3;
      int nt   = sub / 6;             // 0..3
      int cw   = tl * TW + nt * 16 + (sl & 15);
      int q    = sl >> 4;
      const unsigned short* src =
          EHu + (size_t)pl * 65536 + (size_t)cw * 64 + half * 32 + q * 8;
      gl_lds16(src, &lbuf[s][(size_t)slot * 8]);
    }
  };

  bf16x8 a[12];                       // A-frags: a[mt*6 + plane*2 + half]
  #pragma unroll
  for (int mt = 0; mt < 2; ++mt) {
    size_t ao = (size_t)(rowbase + mt * 16 + col) * 64 + quad * 8;
    a[mt * 6 + 0] = *(const bf16x8*)(XH + ao);
    a[mt * 6 + 1] = *(const bf16x8*)(XH + ao + 32);
    a[mt * 6 + 2] = *(const bf16x8*)(XM + ao);
    a[mt * 6 + 3] = *(const bf16x8*)(XM + ao + 32);
    a[mt * 6 + 4] = *(const bf16x8*)(XL + ao);
    a[mt * 6 + 5] = *(const bf16x8*)(XL + ao + 32);
  }
  float x2v[8];
  #pragma unroll
  for (int mt = 0; mt < 2; ++mt)
    #pragma unroll
    for (int r = 0; r < 4; ++r)
      x2v[mt * 4 + r] = X2[rowbase + mt * 16 + quad * 4 + r];

  // keep frags opaque so the allocator cannot rematerialize from global
  #pragma unroll
  for (int i = 0; i < 12; ++i) asm volatile("" : "+v"(a[i]));
  #pragma unroll
  for (int i = 0; i < 8; ++i) asm volatile("" : "+v"(x2v[i]));

  float best[8];
  int bidx[8];
  #pragma unroll
  for (int i = 0; i < 8; ++i) { best[i] = 3.4e38f; bidx[i] = 0; }

  stage(0, 0);

  for (int tl = 0; tl < Ec / TW; ++tl) {
    __syncthreads();                   // stage(tl) complete (vmcnt drained)
    if (tl + 1 < Ec / TW) stage(tl + 1, (tl + 1) & 1);
    const unsigned short* lb = lbuf[tl & 1];

    #pragma unroll
    for (int np = 0; np < 2; ++np) {   // pairs of N-tiles: (0,1), (2,3)
      bf16x8 b0[6], b1[6];
      #pragma unroll
      for (int pl = 0; pl < 3; ++pl)
        #pragma unroll
        for (int h = 0; h < 2; ++h) {
          b0[pl * 2 + h] = *(const bf16x8*)(
              lb + ((size_t)(((((2 * np + 0) * 3 + pl) * 2 + h)) * 64 + lane)) * 8);
          b1[pl * 2 + h] = *(const bf16x8*)(
              lb + ((size_t)(((((2 * np + 1) * 3 + pl) * 2 + h)) * 64 + lane)) * 8);
        }
      const float e2v0 = E2[tl * TW + (2 * np + 0) * 16 + col];
      const float e2v1 = E2[tl * TW + (2 * np + 1) * 16 + col];

      f32x4 acc00 = {0.f, 0.f, 0.f, 0.f};  // rowtile0 x ntile0
      f32x4 acc01 = {0.f, 0.f, 0.f, 0.f};  // rowtile1 x ntile0
      f32x4 acc10 = {0.f, 0.f, 0.f, 0.f};  // rowtile0 x ntile1
      f32x4 acc11 = {0.f, 0.f, 0.f, 0.f};  // rowtile1 x ntile1
      const int PA[6] = {0, 0, 1, 1, 0, 2};   // products hh,hm,mh,mm,hl,lh
      const int PB[6] = {0, 1, 0, 1, 2, 0};
      #pragma unroll
      for (int p = 0; p < 6; ++p) {
        #pragma unroll
        for (int s = 0; s < 2; ++s) {
          bf16x8 a0 = a[PA[p] * 2 + s];
          bf16x8 a1 = a[6 + PA[p] * 2 + s];
          bf16x8 f0 = b0[PB[p] * 2 + s];
          bf16x8 f1 = b1[PB[p] * 2 + s];
          acc00 = __builtin_amdgcn_mfma_f32_16x16x32_bf16(a0, f0, acc00, 0, 0, 0);
          acc10 = __builtin_amdgcn_mfma_f32_16x16x32_bf16(a0, f1, acc10, 0, 0, 0);
          acc01 = __builtin_amdgcn_mfma_f32_16x16x32_bf16(a1, f0, acc01, 0, 0, 0);
          acc11 = __builtin_amdgcn_mfma_f32_16x16x32_bf16(a1, f1, acc11, 0, 0, 0);
        }
      }

      const int cw0 = tl * TW + (2 * np + 0) * 16 + col;
      const int cw1 = tl * TW + (2 * np + 1) * 16 + col;
      #pragma unroll
      for (int r = 0; r < 4; ++r) {
        {
          float q = __builtin_fmaf(-2.0f, acc00[r], e2v0);
          q = q + x2v[r];
          if (q < best[r]) { best[r] = q; bidx[r] = cw0; }
        }
        {
          float q = __builtin_fmaf(-2.0f, acc01[r], e2v0);
          q = q + x2v[4 + r];
          if (q < best[4 + r]) { best[4 + r] = q; bidx[4 + r] = cw0; }
        }
        {
          float q = __builtin_fmaf(-2.0f, acc10[r], e2v1);
          q = q + x2v[r];
          if (q < best[r]) { best[r] = q; bidx[r] = cw1; }
        }
        {
          float q = __builtin_fmaf(-2.0f, acc11[r], e2v1);
          q = q + x2v[4 + r];
          if (q < best[4 + r]) { best[4 + r] = q; bidx[4 + r] = cw1; }
        }
      }
    }
  }

  // cross-lane argmin within each 16-lane col group (ties -> lowest cw index)
  #pragma unroll
  for (int i = 0; i < 8; ++i) {
    float bq = best[i];
    int bi = bidx[i];
    #pragma unroll
    for (int m = 1; m <= 8; m <<= 1) {
      float qo = __shfl_xor(bq, m, 64);
      int io = __shfl_xor(bi, m, 64);
      bool take = (qo < bq) || (qo == bq && io < bi);
      bq = take ? qo : bq;
      bi = take ? io : bi;
    }
    if (col == 0) {
      int mt = i >> 2, r = i & 3;
      int row = rowbase + mt * 16 + quad * 4 + r;
      out[O_IDX + row] = (float)bi;   // C row = quad*4+reg [m89]
    }
  }
}

// ---- esum_partial: segmented reduction of x into embed_sum via LDS. ----
__global__ __launch_bounds__(512) void esum_partial(float* __restrict__ out,
                                                    float* __restrict__ ws) {
  const int c = blockIdx.x;       // row chunk, 4096 rows
  const int s = blockIdx.y;       // d-slice of 4
  __shared__ float acc[4 * 1025];
  __shared__ float cnt[1024];
  for (int i = threadIdx.x; i < 4 * 1025; i += 512) acc[i] = 0.f;
  if (s == 0)
    for (int i = threadIdx.x; i < 1024; i += 512) cnt[i] = 0.f;
  __syncthreads();

  const unsigned short* XH = (const unsigned short*)(out + S_XH);
  const unsigned short* XM = (const unsigned short*)(out + S_XM);
  const unsigned short* XL = (const unsigned short*)(out + S_XL);

  #pragma unroll 2
  for (int it = 0; it < 8; ++it) {
    const int r = c * 4096 + it * 512 + threadIdx.x;
    const int bi = (int)out[O_IDX + r];
    const size_t off = (size_t)r * 64 + s * 4;
    const uint2 h = *(const uint2*)(XH + off);
    const uint2 m = *(const uint2*)(XM + off);
    const uint2 l = *(const uint2*)(XL + off);

#define DOPAIR(k, HW, MW, LW)                                                  \
    {                                                                          \
      float v0 = (bf16val((unsigned short)(HW)) +                              \
                  bf16val((unsigned short)(MW))) +                             \
                 bf16val((unsigned short)(LW));                                \
      float v1 = (bf16val((unsigned short)((HW) >> 16)) +                      \
                  bf16val((unsigned short)((MW) >> 16))) +                     \
                 bf16val((unsigned short)((LW) >> 16));                        \
      atomicAdd(&acc[(2 * (k) + 0) * 1025 + bi], v0);                          \
      atomicAdd(&acc[(2 * (k) + 1) * 1025 + bi], v1);                          \
    }
    DOPAIR(0, h.x, m.x, l.x)
    DOPAIR(1, h.y, m.y, l.y)
#undef DOPAIR
    if (s == 0) atomicAdd(&cnt[bi], 1.0f);
  }
  __syncthreads();

  float* part = out + S_P + ((size_t)c * 64 + s * 4) * 1024;
  for (int i = threadIdx.x; i < 4096; i += 512)
    part[i] = acc[(i >> 10) * 1025 + (i & 1023)];
  if (s == 0)
    for (int i = threadIdx.x; i < 1024; i += 512)
      atomicAdd(&ws[i], cnt[i]);
}

// ---- finalize_a: ema_size update + normalization (needs only counts) ----
__global__ __launch_bounds__(1024) void finalize_a(
    const float* __restrict__ ema_size, float* __restrict__ ws,
    float* __restrict__ out) {
  const int e = threadIdx.x;
  float ns = DECAYF * ema_size[e] + OMDF * ws[e];
  __shared__ float red[1024];
  red[e] = ns;
  __syncthreads();
  for (int s = 512; s > 0; s >>= 1) {
    if (e < s) red[e] += red[e + s];
    __syncthreads();
  }
  float n = red[0];
  float v = ((ns + EPSF) / (n + (float)Ec * EPSF)) * n;
  out[O_ESZ + e] = v;
  ws[66560 + e] = v;                   // norm
}

// ---- esum_finalize_w: fused esum_reduce + finalize_b ----
__global__ __launch_bounds__(256) void esum_finalize_w(
    const float* __restrict__ ema_w, const float* __restrict__ ws,
    float* __restrict__ out) {
  const int i = blockIdx.x * 256 + threadIdx.x;  // 0..65535 (= d*1024+e)
  float v = 0.f;
  #pragma unroll
  for (int c = 0; c < 16; ++c) v += out[S_P + (size_t)c * 65536 + i];
  int d = i >> 10;
  int e = i & (Ec - 1);
  float w = DECAYF * ema_w[i] + OMDF * v;
  out[O_EMW + i] = w;
  out[O_EMB + e * Dc + d] = w / ws[66560 + e];
}

// ---- epilogue: pure streaming: read x/idx, gather emb, write embed_idx+qx ----
__global__ __launch_bounds__(256) void epilogue_kernel(
    const float* __restrict__ x, const float* __restrict__ emb,
    float* __restrict__ out) {
  const int row = blockIdx.x * 256 + threadIdx.x;
  const int b = row >> 12, t = row & (Tc - 1);
  const float* xrow = x + (size_t)b * Dc * Tc + t;

  const int bi = (int)out[O_IDX + row];

  const float4* eb = (const float4*)(emb + (size_t)bi * Dc);
  float* qx_base = out + O_QX + (size_t)b * Dc * Tc + t;
  float4* ei_base = (float4*)(out + O_EI + (size_t)row * Dc);

  #pragma unroll
  for (int k = 0; k < 16; ++k) {
    float4 ev = eb[k];
    ei_base[k] = ev;
    {
      const int d = 4 * k + 0; float xd = xrow[(size_t)d * Tc];
      float diff = ev.x - xd;
      qx_base[(size_t)d * Tc] = xd + diff;
    }
    {
      const int d = 4 * k + 1; float xd = xrow[(size_t)d * Tc];
      float diff = ev.y - xd;
      qx_base[(size_t)d * Tc] = xd + diff;
    }
    {
      const int d = 4 * k + 2; float xd = xrow[(size_t)d * Tc];
      float diff = ev.z - xd;
      qx_base[(size_t)d * Tc] = xd + diff;
    }
    {
      const int d = 4 * k + 3; float xd = xrow[(size_t)d * Tc];
      float diff = ev.w - xd;
      qx_base[(size_t)d * Tc] = xd + diff;
    }
  }
}

extern "C" void kernel_launch(void* const* d_in, const int* in_sizes, int n_in,
                              void* d_out, int out_size, void* d_ws, size_t ws_size,
                              hipStream_t stream) {
  const float* x        = (const float*)d_in[0];
  const float* emb      = (const float*)d_in[1];
  const float* ema_size = (const float*)d_in[2];
  const float* ema_w    = (const float*)d_in[3];
  float* out = (float*)d_out;
  float* ws  = (float*)d_ws;

  decomp_x<<<NROW / 256, 256, 0, stream>>>(x, out);
  decomp_e<<<Ec / 256, 256, 0, stream>>>(emb, out, ws);   // also zeroes counts
  gemm_argmin<<<NROW / 256, 512, 0, stream>>>(out);
  esum_partial<<<dim3(16, 16), 512, 0, stream>>>(out, ws);
  finalize_a<<<1, 1024, 0, stream>>>(ema_size, ws, out);
  esum_finalize_w<<<Ec * Dc / 256, 256, 0, stream>>>(ema_w, ws, out);
  epilogue_kernel<<<NROW / 256, 256, 0, stream>>>(x, emb, out);
}